// Round 2
// baseline (840.947 us; speedup 1.0000x reference)
//
#include <hip/hip_runtime.h>

#define NN 50000
#define NE 800000
#define NS 4
#define NT (NS * NN)          // 200000
#define D 128
#define SB2 782               // ceil(NT/256)
#define EW_SCALE 262144.0f    // 2^18 fixed-point for packed degree
#define EW_INV (1.0f / 262144.0f)

typedef unsigned long long ull;

__device__ __forceinline__ unsigned short f2bf(float f) {
  unsigned int u = __float_as_uint(f);
  u += 0x7fffu + ((u >> 16) & 1u);  // RNE
  return (unsigned short)(u >> 16);
}
__device__ __forceinline__ float bf2f(unsigned short h) {
  return __uint_as_float((unsigned int)h << 16);
}

// ---------------- GEMM: H0h[M x D] (bf16) = X[M x D] @ W[D x D] ----------------
// B-operand read directly from global (W is 64KB, L1/L2-resident, shared by all
// blocks) — no ws staging, no per-chunk barriers, no LDS bank conflicts.

__global__ __launch_bounds__(256) void gemm_plain_bf16out(
    const float* __restrict__ X, const float* __restrict__ W,
    unsigned short* __restrict__ O, int M) {
  __shared__ float xs[64 * 130];
  const int tid = threadIdx.x;
  const int r0 = blockIdx.x * 64;
  for (int i = tid; i < 64 * 64; i += 256) {
    int row = i >> 6, kh = i & 63;
    float2 v = make_float2(0.f, 0.f);
    int gr = r0 + row;
    if (gr < M) v = *(const float2*)&X[(size_t)gr * D + kh * 2];
    *(float2*)&xs[row * 130 + kh * 2] = v;
  }
  const int tx = tid & 15, ty = tid >> 4;
  const float* Wb = W + tx * 8;
  float acc[4][8];
#pragma unroll
  for (int i = 0; i < 4; i++)
#pragma unroll
    for (int j = 0; j < 8; j++) acc[i][j] = 0.f;

  __syncthreads();
#pragma unroll 4
  for (int k = 0; k < D; k += 2) {
    float2 a[4];
#pragma unroll
    for (int i = 0; i < 4; i++) a[i] = *(const float2*)&xs[(ty * 4 + i) * 130 + k];
    float4 b00 = *(const float4*)&Wb[(size_t)k * D];
    float4 b01 = *(const float4*)&Wb[(size_t)k * D + 4];
    float4 b10 = *(const float4*)&Wb[(size_t)(k + 1) * D];
    float4 b11 = *(const float4*)&Wb[(size_t)(k + 1) * D + 4];
    float b0[8] = {b00.x, b00.y, b00.z, b00.w, b01.x, b01.y, b01.z, b01.w};
    float b1[8] = {b10.x, b10.y, b10.z, b10.w, b11.x, b11.y, b11.z, b11.w};
#pragma unroll
    for (int i = 0; i < 4; i++)
#pragma unroll
      for (int j = 0; j < 8; j++) {
        acc[i][j] += a[i].x * b0[j];
        acc[i][j] += a[i].y * b1[j];
      }
  }
#pragma unroll
  for (int i = 0; i < 4; i++) {
    int gr = r0 + ty * 4 + i;
    if (gr < M) {
      ushort4 o0, o1;
      o0.x = f2bf(acc[i][0]); o0.y = f2bf(acc[i][1]);
      o0.z = f2bf(acc[i][2]); o0.w = f2bf(acc[i][3]);
      o1.x = f2bf(acc[i][4]); o1.y = f2bf(acc[i][5]);
      o1.z = f2bf(acc[i][6]); o1.w = f2bf(acc[i][7]);
      *(ushort4*)&O[(size_t)gr * D + tx * 8] = o0;
      *(ushort4*)&O[(size_t)gr * D + tx * 8 + 4] = o1;
    }
  }
}

// ---------------- CSR build, batched over all 4 scales ----------------

__global__ __launch_bounds__(256) void initp_k(ull* __restrict__ packed, int n) {
  int i = blockIdx.x * 256 + threadIdx.x;
  if (i < n) packed[i] = 0ULL;
}

// grid (3125, NS). ONE 64-bit atomic per edge; old high word = slot in dst bucket.
__global__ __launch_bounds__(256) void countpos_all_k(const int* __restrict__ ei,
                                                      const float* __restrict__ ewA,
                                                      ull* __restrict__ packedA,
                                                      int* __restrict__ posA) {
  const int t = blockIdx.y;
  const int e = blockIdx.x * 256 + threadIdx.x;
  if (e < NE) {
    const int* dst = ei + (size_t)t * 2 * NE + NE;
    int d = dst[e];
    float w = ewA[(size_t)t * NE + e];
    ull add = (1ULL << 32) | (ull)__float2uint_rn(w * EW_SCALE);
    ull old = atomicAdd(&packedA[t * NN + d], add);
    posA[(size_t)t * NE + e] = (int)(old >> 32);
  }
}

// unpack + per-block partial sum (fused). grid SB2 over NT.
__global__ __launch_bounds__(256) void unpack_scan_k(const ull* __restrict__ packedA,
                                                     float* __restrict__ dinvA,
                                                     int* __restrict__ cntA,
                                                     int* __restrict__ partial) {
  __shared__ int sm[256];
  const int tid = threadIdx.x;
  const int i = blockIdx.x * 256 + tid;
  int c = 0;
  if (i < NT) {
    ull p = packedA[i];
    c = (int)(p >> 32);
    cntA[i] = c;
    float deg = 1.0f + (float)(unsigned int)(p & 0xffffffffULL) * EW_INV;
    dinvA[i] = rsqrtf(deg);
  }
  sm[tid] = c;
  __syncthreads();
  for (int off = 128; off > 0; off >>= 1) {
    if (tid < off) sm[tid] += sm[tid + off];
    __syncthreads();
  }
  if (tid == 0) partial[blockIdx.x] = sm[0];
}

// single block: exclusive scan of SB2 partials (chunked serial + block scan)
__global__ __launch_bounds__(256) void scan_top_k(const int* __restrict__ partial,
                                                  int* __restrict__ poffs, int nb) {
  __shared__ int sm[256];
  const int t = threadIdx.x;
  const int chunk = (nb + 255) >> 8;
  const int lo = t * chunk;
  const int hi = min(lo + chunk, nb);
  int s = 0;
  for (int i = lo; i < hi; i++) s += partial[i];
  sm[t] = s;
  __syncthreads();
  for (int off = 1; off < 256; off <<= 1) {
    int u = (t >= off) ? sm[t - off] : 0;
    __syncthreads();
    sm[t] += u;
    __syncthreads();
  }
  int run = sm[t] - s;  // exclusive
  for (int i = lo; i < hi; i++) {
    poffs[i] = run;
    run += partial[i];
  }
}

__global__ __launch_bounds__(256) void scan_write_k(const int* __restrict__ cntA,
                                                    const int* __restrict__ poffs,
                                                    int* __restrict__ offsA) {
  __shared__ int sm[256];
  const int t = threadIdx.x;
  const int i = blockIdx.x * 256 + t;
  int v = (i < NT) ? cntA[i] : 0;
  sm[t] = v;
  __syncthreads();
  for (int off = 1; off < 256; off <<= 1) {
    int u = (t >= off) ? sm[t - off] : 0;
    __syncthreads();
    sm[t] += u;
    __syncthreads();
  }
  if (i < NT) offsA[i] = poffs[blockIdx.x] + sm[t] - v;
}

// grid (3125, NS): eeA[offsA[t*NN+d] + pos] = (src, norm_bits). No atomics.
// Global scan => scale t's segment is exactly [t*NE, (t+1)*NE).
__global__ __launch_bounds__(256) void fill_all_k(const int* __restrict__ ei,
                                                  const float* __restrict__ ewA,
                                                  const float* __restrict__ dinvA,
                                                  const int* __restrict__ offsA,
                                                  const int* __restrict__ posA,
                                                  int2* __restrict__ eeA) {
  const int t = blockIdx.y;
  const int e = blockIdx.x * 256 + threadIdx.x;
  if (e < NE) {
    const int* src = ei + (size_t)t * 2 * NE;
    const int* dst = src + NE;
    int s = src[e], d = dst[e];
    float w = ewA[(size_t)t * NE + e] * dinvA[t * NN + s] * dinvA[t * NN + d];
    eeA[offsA[t * NN + d] + posA[(size_t)t * NE + e]] = make_int2(s, __float_as_int(w));
  }
}

// ---------------- layer-1 gather, batched: grid (6250, NS) ----------------
// Zh_t = bf16(prelu(Agg(H0h) + b0)); 32 lanes/node, ushort4/lane, fp32 acc.
// Edge loop unrolled 8 deep: 2 latency exposures (eeA, rows) per 8 edges.
__global__ __launch_bounds__(256) void gather1_all_k(
    const unsigned short* __restrict__ H, const int* __restrict__ offsA,
    const int* __restrict__ cntA, const int2* __restrict__ eeA,
    const float* __restrict__ dinvA, const float* __restrict__ bias,
    const float* __restrict__ pa, unsigned short* __restrict__ ZhA) {
  const int t = blockIdx.y;
  int g = blockIdx.x * 256 + threadIdx.x;
  int wid = g >> 5;
  int lane = g & 31;
  if (wid >= NN) return;
  const int base = t * NN + wid;
  const int st = offsA[base];
  const int len = cntA[base];
  const int c = lane * 4;
  float ax = 0.f, ay = 0.f, az = 0.f, aw = 0.f;
  int j = 0;
  for (; j + 8 <= len; j += 8) {
    int2 p0 = eeA[st + j];
    int2 p1 = eeA[st + j + 1];
    int2 p2 = eeA[st + j + 2];
    int2 p3 = eeA[st + j + 3];
    int2 p4 = eeA[st + j + 4];
    int2 p5 = eeA[st + j + 5];
    int2 p6 = eeA[st + j + 6];
    int2 p7 = eeA[st + j + 7];
    ushort4 v0 = *(const ushort4*)&H[(size_t)p0.x * D + c];
    ushort4 v1 = *(const ushort4*)&H[(size_t)p1.x * D + c];
    ushort4 v2 = *(const ushort4*)&H[(size_t)p2.x * D + c];
    ushort4 v3 = *(const ushort4*)&H[(size_t)p3.x * D + c];
    ushort4 v4 = *(const ushort4*)&H[(size_t)p4.x * D + c];
    ushort4 v5 = *(const ushort4*)&H[(size_t)p5.x * D + c];
    ushort4 v6 = *(const ushort4*)&H[(size_t)p6.x * D + c];
    ushort4 v7 = *(const ushort4*)&H[(size_t)p7.x * D + c];
    float w0 = __int_as_float(p0.y), w1 = __int_as_float(p1.y);
    float w2 = __int_as_float(p2.y), w3 = __int_as_float(p3.y);
    float w4 = __int_as_float(p4.y), w5 = __int_as_float(p5.y);
    float w6 = __int_as_float(p6.y), w7 = __int_as_float(p7.y);
    ax += w0 * bf2f(v0.x) + w1 * bf2f(v1.x) + w2 * bf2f(v2.x) + w3 * bf2f(v3.x);
    ay += w0 * bf2f(v0.y) + w1 * bf2f(v1.y) + w2 * bf2f(v2.y) + w3 * bf2f(v3.y);
    az += w0 * bf2f(v0.z) + w1 * bf2f(v1.z) + w2 * bf2f(v2.z) + w3 * bf2f(v3.z);
    aw += w0 * bf2f(v0.w) + w1 * bf2f(v1.w) + w2 * bf2f(v2.w) + w3 * bf2f(v3.w);
    ax += w4 * bf2f(v4.x) + w5 * bf2f(v5.x) + w6 * bf2f(v6.x) + w7 * bf2f(v7.x);
    ay += w4 * bf2f(v4.y) + w5 * bf2f(v5.y) + w6 * bf2f(v6.y) + w7 * bf2f(v7.y);
    az += w4 * bf2f(v4.z) + w5 * bf2f(v5.z) + w6 * bf2f(v6.z) + w7 * bf2f(v7.z);
    aw += w4 * bf2f(v4.w) + w5 * bf2f(v5.w) + w6 * bf2f(v6.w) + w7 * bf2f(v7.w);
  }
  for (; j + 4 <= len; j += 4) {
    int2 p0 = eeA[st + j];
    int2 p1 = eeA[st + j + 1];
    int2 p2 = eeA[st + j + 2];
    int2 p3 = eeA[st + j + 3];
    ushort4 v0 = *(const ushort4*)&H[(size_t)p0.x * D + c];
    ushort4 v1 = *(const ushort4*)&H[(size_t)p1.x * D + c];
    ushort4 v2 = *(const ushort4*)&H[(size_t)p2.x * D + c];
    ushort4 v3 = *(const ushort4*)&H[(size_t)p3.x * D + c];
    float w0 = __int_as_float(p0.y), w1 = __int_as_float(p1.y);
    float w2 = __int_as_float(p2.y), w3 = __int_as_float(p3.y);
    ax += w0 * bf2f(v0.x) + w1 * bf2f(v1.x) + w2 * bf2f(v2.x) + w3 * bf2f(v3.x);
    ay += w0 * bf2f(v0.y) + w1 * bf2f(v1.y) + w2 * bf2f(v2.y) + w3 * bf2f(v3.y);
    az += w0 * bf2f(v0.z) + w1 * bf2f(v1.z) + w2 * bf2f(v2.z) + w3 * bf2f(v3.z);
    aw += w0 * bf2f(v0.w) + w1 * bf2f(v1.w) + w2 * bf2f(v2.w) + w3 * bf2f(v3.w);
  }
  for (; j < len; j++) {
    int2 p = eeA[st + j];
    float w = __int_as_float(p.y);
    ushort4 v = *(const ushort4*)&H[(size_t)p.x * D + c];
    ax += w * bf2f(v.x);
    ay += w * bf2f(v.y);
    az += w * bf2f(v.z);
    aw += w * bf2f(v.w);
  }
  float dv = dinvA[base];
  float d2 = dv * dv;
  ushort4 h = *(const ushort4*)&H[(size_t)wid * D + c];
  ax += d2 * bf2f(h.x) + bias[c];
  ay += d2 * bf2f(h.y) + bias[c + 1];
  az += d2 * bf2f(h.z) + bias[c + 2];
  aw += d2 * bf2f(h.w) + bias[c + 3];
  ax = ax > 0.f ? ax : pa[c] * ax;
  ay = ay > 0.f ? ay : pa[c + 1] * ay;
  az = az > 0.f ? az : pa[c + 2] * az;
  aw = aw > 0.f ? aw : pa[c + 3] * aw;
  ushort4 o;
  o.x = f2bf(ax); o.y = f2bf(ay); o.z = f2bf(az); o.w = f2bf(aw);
  *(ushort4*)&ZhA[(size_t)t * NN * D + (size_t)wid * D + c] = o;
}

// ---------------- layer-2 fused: Agg(Zh_t) -> LDS -> @W1 + b1 -> prelu -> out ----
// grid (1563, NS). 32-row tile, xs only (16896 B LDS) => 8 blocks/CU (32 waves,
// 100% occupancy cap). B-operand (W1, 64KB) read directly from global — it is
// L1/L2-resident across all 6252 blocks. This removes the ws staging loop, its
// 4-way ds_read_b128 bank conflicts (the 2.56e7 conflict cycles measured in r1),
// and 15 of the 16 barriers per block. xs a-reads use float2 over k-pairs.
__global__ __launch_bounds__(256, 8) void l2_fused_k(
    const unsigned short* __restrict__ ZhA, const int* __restrict__ offsA,
    const int* __restrict__ cntA, const int2* __restrict__ eeA,
    const float* __restrict__ dinvA, const float* __restrict__ W,
    const float* __restrict__ bias, const float* __restrict__ pa,
    float* __restrict__ out) {
  __shared__ float xs[32 * 132];
  const int t = blockIdx.y;
  const int r0 = blockIdx.x * 32;
  const int tid = threadIdx.x;
  const unsigned short* Z = ZhA + (size_t)t * NN * D;

  // ---- phase 1: gather 32 aggregated rows into xs ----
  {
    const int grp = tid >> 5;   // 0..7
    const int lane = tid & 31;
    const int c = lane * 4;
    for (int it = 0; it < 4; it++) {
      const int row = grp * 4 + it;
      const int node = r0 + row;
      float ax = 0.f, ay = 0.f, az = 0.f, aw = 0.f;
      if (node < NN) {
        const int base = t * NN + node;
        const int st = offsA[base];
        const int len = cntA[base];
        int j = 0;
        for (; j + 4 <= len; j += 4) {
          int2 p0 = eeA[st + j];
          int2 p1 = eeA[st + j + 1];
          int2 p2 = eeA[st + j + 2];
          int2 p3 = eeA[st + j + 3];
          ushort4 v0 = *(const ushort4*)&Z[(size_t)p0.x * D + c];
          ushort4 v1 = *(const ushort4*)&Z[(size_t)p1.x * D + c];
          ushort4 v2 = *(const ushort4*)&Z[(size_t)p2.x * D + c];
          ushort4 v3 = *(const ushort4*)&Z[(size_t)p3.x * D + c];
          float w0 = __int_as_float(p0.y), w1 = __int_as_float(p1.y);
          float w2 = __int_as_float(p2.y), w3 = __int_as_float(p3.y);
          ax += w0 * bf2f(v0.x) + w1 * bf2f(v1.x) + w2 * bf2f(v2.x) + w3 * bf2f(v3.x);
          ay += w0 * bf2f(v0.y) + w1 * bf2f(v1.y) + w2 * bf2f(v2.y) + w3 * bf2f(v3.y);
          az += w0 * bf2f(v0.z) + w1 * bf2f(v1.z) + w2 * bf2f(v2.z) + w3 * bf2f(v3.z);
          aw += w0 * bf2f(v0.w) + w1 * bf2f(v1.w) + w2 * bf2f(v2.w) + w3 * bf2f(v3.w);
        }
        for (; j < len; j++) {
          int2 p = eeA[st + j];
          float w = __int_as_float(p.y);
          ushort4 v = *(const ushort4*)&Z[(size_t)p.x * D + c];
          ax += w * bf2f(v.x);
          ay += w * bf2f(v.y);
          az += w * bf2f(v.z);
          aw += w * bf2f(v.w);
        }
        float dv = dinvA[base];
        float d2 = dv * dv;
        ushort4 h = *(const ushort4*)&Z[(size_t)node * D + c];
        ax += d2 * bf2f(h.x);
        ay += d2 * bf2f(h.y);
        az += d2 * bf2f(h.z);
        aw += d2 * bf2f(h.w);
      }
      *(float4*)&xs[row * 132 + c] = make_float4(ax, ay, az, aw);
    }
  }

  // ---- phase 2: GEMM xs @ W + bias, prelu, store fp32 ----
  const int tx = tid & 15, ty = tid >> 4;   // tx: 8 cols, ty: 2 rows
  const float* Wb = W + tx * 8;
  float bv[8], av[8];
#pragma unroll
  for (int j = 0; j < 8; j++) {
    bv[j] = bias[tx * 8 + j];
    av[j] = pa[tx * 8 + j];
  }
  float acc[2][8];
#pragma unroll
  for (int i = 0; i < 2; i++)
#pragma unroll
    for (int j = 0; j < 8; j++) acc[i][j] = 0.f;

  __syncthreads();  // closes phase 1
#pragma unroll 4
  for (int k = 0; k < D; k += 2) {
    float2 a0 = *(const float2*)&xs[(ty * 2) * 132 + k];
    float2 a1 = *(const float2*)&xs[(ty * 2 + 1) * 132 + k];
    float4 b00 = *(const float4*)&Wb[(size_t)k * D];
    float4 b01 = *(const float4*)&Wb[(size_t)k * D + 4];
    float4 b10 = *(const float4*)&Wb[(size_t)(k + 1) * D];
    float4 b11 = *(const float4*)&Wb[(size_t)(k + 1) * D + 4];
    float b0[8] = {b00.x, b00.y, b00.z, b00.w, b01.x, b01.y, b01.z, b01.w};
    float b1[8] = {b10.x, b10.y, b10.z, b10.w, b11.x, b11.y, b11.z, b11.w};
#pragma unroll
    for (int j = 0; j < 8; j++) {
      acc[0][j] += a0.x * b0[j];
      acc[1][j] += a1.x * b0[j];
      acc[0][j] += a0.y * b1[j];
      acc[1][j] += a1.y * b1[j];
    }
  }
  float* outT = out + (size_t)t * NN * D;
#pragma unroll
  for (int i = 0; i < 2; i++) {
    int gr = r0 + ty * 2 + i;
    if (gr < NN) {
#pragma unroll
      for (int j = 0; j < 8; j++) {
        float v = acc[i][j] + bv[j];
        acc[i][j] = v > 0.f ? v : av[j] * v;
      }
      float4 o0 = make_float4(acc[i][0], acc[i][1], acc[i][2], acc[i][3]);
      float4 o1 = make_float4(acc[i][4], acc[i][5], acc[i][6], acc[i][7]);
      *(float4*)&outT[(size_t)gr * D + tx * 8] = o0;
      *(float4*)&outT[(size_t)gr * D + tx * 8 + 4] = o1;
    }
  }
}

// ---------------- launch ----------------

extern "C" void kernel_launch(void* const* d_in, const int* in_sizes, int n_in,
                              void* d_out, int out_size, void* d_ws, size_t ws_size,
                              hipStream_t stream) {
  const float* x = (const float*)d_in[0];
  const int* ei = (const int*)d_in[1];       // [4][2][NE] int32
  const float* ew = (const float*)d_in[2];   // [4][NE]
  const float* W0 = (const float*)d_in[3];
  const float* b0 = (const float*)d_in[4];
  const float* W1 = (const float*)d_in[5];
  const float* b1 = (const float*)d_in[6];
  const float* pa = (const float*)d_in[7];
  float* out = (float*)d_out;                // [4][NN][D] fp32

  // ws layout (d_ws assumed >=8B aligned; all segment sizes keep 8B alignment)
  ull* packedA = (ull*)d_ws;                              // NT ull      (1.6 MB)
  int2* eeA = (int2*)(packedA + NT);                      // NS*NE int2  (25.6 MB)
  int* posA = (int*)(eeA + (size_t)NS * NE);              // NS*NE int   (12.8 MB)
  float* dinvA = (float*)(posA + (size_t)NS * NE);        // NT f32
  int* cntA = (int*)(dinvA + NT);                         // NT
  int* offsA = cntA + NT;                                 // NT
  int* partial = offsA + NT;                              // 1024
  int* poffs = partial + 1024;                            // 1024
  unsigned short* H0h = (unsigned short*)(poffs + 1024);  // NN*D bf16 (12.8 MB)
  unsigned short* ZhA = H0h + (size_t)NN * D;             // NS*NN*D bf16 (51.2 MB)

  const int gGemm = (NN + 63) / 64;           // 782
  const int gL2 = (NN + 31) / 32;             // 1563
  const int gEdge = (NE + 255) / 256;         // 3125
  const int gInit = (NT + 255) / 256;         // 782
  const int gGather = (NN * 32 + 255) / 256;  // 6250

  // H0h = bf16(x @ W0), shared across scales (independent of CSR build)
  gemm_plain_bf16out<<<gGemm, 256, 0, stream>>>(x, W0, H0h, NN);

  // batched CSR build for all 4 scales
  initp_k<<<gInit, 256, 0, stream>>>(packedA, NT);
  countpos_all_k<<<dim3(gEdge, NS), 256, 0, stream>>>(ei, ew, packedA, posA);
  unpack_scan_k<<<SB2, 256, 0, stream>>>(packedA, dinvA, cntA, partial);
  scan_top_k<<<1, 256, 0, stream>>>(partial, poffs, SB2);
  scan_write_k<<<SB2, 256, 0, stream>>>(cntA, poffs, offsA);
  fill_all_k<<<dim3(gEdge, NS), 256, 0, stream>>>(ei, ew, dinvA, offsA, posA, eeA);

  // layer 1 (all scales): ZhA[t] = bf16(prelu(Agg_t(H0h) + b0))
  gather1_all_k<<<dim3(gGather, NS), 256, 0, stream>>>(H0h, offsA, cntA, eeA,
                                                       dinvA, b0, pa, ZhA);
  // layer 2 (all scales, fused): out[t] = prelu(Agg_t(ZhA[t]) @ W1 + b1)
  l2_fused_k<<<dim3(gL2, NS), 256, 0, stream>>>(ZhA, offsA, cntA, eeA, dinvA,
                                                W1, b1, pa, out);
}

// Round 3
// 748.585 us; speedup vs baseline: 1.1234x; 1.1234x over previous
//
#include <hip/hip_runtime.h>

#define NN 50000
#define NE 800000
#define NS 4
#define NT (NS * NN)          // 200000
#define D 128
#define SB2 782               // ceil(NT/256)
#define EW_SCALE 262144.0f    // 2^18 fixed-point for packed degree
#define EW_INV (1.0f / 262144.0f)

typedef unsigned long long ull;

__device__ __forceinline__ unsigned short f2bf(float f) {
  unsigned int u = __float_as_uint(f);
  u += 0x7fffu + ((u >> 16) & 1u);  // RNE
  return (unsigned short)(u >> 16);
}
__device__ __forceinline__ float bf2f(unsigned short h) {
  return __uint_as_float((unsigned int)h << 16);
}

// ---------------- GEMM: H0h[M x D] (bf16) = X[M x D] @ W[D x D] ----------------
// ws-staged. Split-column ownership (cols tx*4 and 64+tx*4): b-reads are 16
// addresses at 16B stride spanning 256B => 2 lanes/bank (free), vs the old
// tx*8 layout's 32B stride => 4-way conflict on every ds_read_b128.

__global__ __launch_bounds__(256) void gemm_plain_bf16out(
    const float* __restrict__ X, const float* __restrict__ W,
    unsigned short* __restrict__ O, int M) {
  __shared__ float xs[64 * 130];
  __shared__ float ws[32 * 128];
  const int tid = threadIdx.x;
  const int r0 = blockIdx.x * 64;
  for (int i = tid; i < 64 * 64; i += 256) {
    int row = i >> 6, kh = i & 63;
    float2 v = make_float2(0.f, 0.f);
    int gr = r0 + row;
    if (gr < M) v = *(const float2*)&X[(size_t)gr * D + kh * 2];
    *(float2*)&xs[row * 130 + kh * 2] = v;
  }
  const int tx = tid & 15, ty = tid >> 4;
  const int c0 = tx * 4;        // cols c0..c0+3
  const int c1 = 64 + tx * 4;   // cols c1..c1+3
  float acc[4][8];
#pragma unroll
  for (int i = 0; i < 4; i++)
#pragma unroll
    for (int j = 0; j < 8; j++) acc[i][j] = 0.f;

  for (int kc = 0; kc < 4; kc++) {
    __syncthreads();
    for (int i = tid; i < 32 * 32; i += 256) {
      ((float4*)ws)[i] = ((const float4*)(W + kc * 32 * D))[i];
    }
    __syncthreads();
#pragma unroll 4
    for (int k2 = 0; k2 < 32; k2++) {
      const int k = kc * 32 + k2;
      float a[4];
#pragma unroll
      for (int j = 0; j < 4; j++) a[j] = xs[(ty * 4 + j) * 130 + k];
      float4 b0 = *(const float4*)&ws[k2 * 128 + c0];
      float4 b1 = *(const float4*)&ws[k2 * 128 + c1];
      float b[8] = {b0.x, b0.y, b0.z, b0.w, b1.x, b1.y, b1.z, b1.w};
#pragma unroll
      for (int i = 0; i < 4; i++)
#pragma unroll
        for (int j = 0; j < 8; j++) acc[i][j] += a[i] * b[j];
    }
  }
#pragma unroll
  for (int i = 0; i < 4; i++) {
    int gr = r0 + ty * 4 + i;
    if (gr < M) {
      ushort4 o0, o1;
      o0.x = f2bf(acc[i][0]); o0.y = f2bf(acc[i][1]);
      o0.z = f2bf(acc[i][2]); o0.w = f2bf(acc[i][3]);
      o1.x = f2bf(acc[i][4]); o1.y = f2bf(acc[i][5]);
      o1.z = f2bf(acc[i][6]); o1.w = f2bf(acc[i][7]);
      *(ushort4*)&O[(size_t)gr * D + c0] = o0;
      *(ushort4*)&O[(size_t)gr * D + c1] = o1;
    }
  }
}

// ---------------- CSR build, batched over all 4 scales ----------------

__global__ __launch_bounds__(256) void initp_k(ull* __restrict__ packed, int n) {
  int i = blockIdx.x * 256 + threadIdx.x;
  if (i < n) packed[i] = 0ULL;
}

// grid (3125, NS). ONE 64-bit atomic per edge; old high word = slot in dst bucket.
__global__ __launch_bounds__(256) void countpos_all_k(const int* __restrict__ ei,
                                                      const float* __restrict__ ewA,
                                                      ull* __restrict__ packedA,
                                                      int* __restrict__ posA) {
  const int t = blockIdx.y;
  const int e = blockIdx.x * 256 + threadIdx.x;
  if (e < NE) {
    const int* dst = ei + (size_t)t * 2 * NE + NE;
    int d = dst[e];
    float w = ewA[(size_t)t * NE + e];
    ull add = (1ULL << 32) | (ull)__float2uint_rn(w * EW_SCALE);
    ull old = atomicAdd(&packedA[t * NN + d], add);
    posA[(size_t)t * NE + e] = (int)(old >> 32);
  }
}

// unpack + per-block partial sum (fused). grid SB2 over NT.
__global__ __launch_bounds__(256) void unpack_scan_k(const ull* __restrict__ packedA,
                                                     float* __restrict__ dinvA,
                                                     int* __restrict__ cntA,
                                                     int* __restrict__ partial) {
  __shared__ int sm[256];
  const int tid = threadIdx.x;
  const int i = blockIdx.x * 256 + tid;
  int c = 0;
  if (i < NT) {
    ull p = packedA[i];
    c = (int)(p >> 32);
    cntA[i] = c;
    float deg = 1.0f + (float)(unsigned int)(p & 0xffffffffULL) * EW_INV;
    dinvA[i] = rsqrtf(deg);
  }
  sm[tid] = c;
  __syncthreads();
  for (int off = 128; off > 0; off >>= 1) {
    if (tid < off) sm[tid] += sm[tid + off];
    __syncthreads();
  }
  if (tid == 0) partial[blockIdx.x] = sm[0];
}

// single block: exclusive scan of SB2 partials (chunked serial + block scan)
__global__ __launch_bounds__(256) void scan_top_k(const int* __restrict__ partial,
                                                  int* __restrict__ poffs, int nb) {
  __shared__ int sm[256];
  const int t = threadIdx.x;
  const int chunk = (nb + 255) >> 8;
  const int lo = t * chunk;
  const int hi = min(lo + chunk, nb);
  int s = 0;
  for (int i = lo; i < hi; i++) s += partial[i];
  sm[t] = s;
  __syncthreads();
  for (int off = 1; off < 256; off <<= 1) {
    int u = (t >= off) ? sm[t - off] : 0;
    __syncthreads();
    sm[t] += u;
    __syncthreads();
  }
  int run = sm[t] - s;  // exclusive
  for (int i = lo; i < hi; i++) {
    poffs[i] = run;
    run += partial[i];
  }
}

__global__ __launch_bounds__(256) void scan_write_k(const int* __restrict__ cntA,
                                                    const int* __restrict__ poffs,
                                                    int* __restrict__ offsA) {
  __shared__ int sm[256];
  const int t = threadIdx.x;
  const int i = blockIdx.x * 256 + t;
  int v = (i < NT) ? cntA[i] : 0;
  sm[t] = v;
  __syncthreads();
  for (int off = 1; off < 256; off <<= 1) {
    int u = (t >= off) ? sm[t - off] : 0;
    __syncthreads();
    sm[t] += u;
    __syncthreads();
  }
  if (i < NT) offsA[i] = poffs[blockIdx.x] + sm[t] - v;
}

// grid (3125, NS): eeA[offsA[t*NN+d] + pos] = (src, norm_bits). No atomics.
// Global scan => scale t's segment is exactly [t*NE, (t+1)*NE).
__global__ __launch_bounds__(256) void fill_all_k(const int* __restrict__ ei,
                                                  const float* __restrict__ ewA,
                                                  const float* __restrict__ dinvA,
                                                  const int* __restrict__ offsA,
                                                  const int* __restrict__ posA,
                                                  int2* __restrict__ eeA) {
  const int t = blockIdx.y;
  const int e = blockIdx.x * 256 + threadIdx.x;
  if (e < NE) {
    const int* src = ei + (size_t)t * 2 * NE;
    const int* dst = src + NE;
    int s = src[e], d = dst[e];
    float w = ewA[(size_t)t * NE + e] * dinvA[t * NN + s] * dinvA[t * NN + d];
    eeA[offsA[t * NN + d] + posA[(size_t)t * NE + e]] = make_int2(s, __float_as_int(w));
  }
}

// ---------------- layer-1 gather, batched: grid (6250, NS) ----------------
// Zh_t = bf16(prelu(Agg(H0h) + b0)); 32 lanes/node, ushort4/lane, fp32 acc.
// Edge loop unrolled 8 deep: 2 latency exposures (eeA, rows) per 8 edges.
__global__ __launch_bounds__(256) void gather1_all_k(
    const unsigned short* __restrict__ H, const int* __restrict__ offsA,
    const int* __restrict__ cntA, const int2* __restrict__ eeA,
    const float* __restrict__ dinvA, const float* __restrict__ bias,
    const float* __restrict__ pa, unsigned short* __restrict__ ZhA) {
  const int t = blockIdx.y;
  int g = blockIdx.x * 256 + threadIdx.x;
  int wid = g >> 5;
  int lane = g & 31;
  if (wid >= NN) return;
  const int base = t * NN + wid;
  const int st = offsA[base];
  const int len = cntA[base];
  const int c = lane * 4;
  float ax = 0.f, ay = 0.f, az = 0.f, aw = 0.f;
  int j = 0;
  for (; j + 8 <= len; j += 8) {
    int2 p0 = eeA[st + j];
    int2 p1 = eeA[st + j + 1];
    int2 p2 = eeA[st + j + 2];
    int2 p3 = eeA[st + j + 3];
    int2 p4 = eeA[st + j + 4];
    int2 p5 = eeA[st + j + 5];
    int2 p6 = eeA[st + j + 6];
    int2 p7 = eeA[st + j + 7];
    ushort4 v0 = *(const ushort4*)&H[(size_t)p0.x * D + c];
    ushort4 v1 = *(const ushort4*)&H[(size_t)p1.x * D + c];
    ushort4 v2 = *(const ushort4*)&H[(size_t)p2.x * D + c];
    ushort4 v3 = *(const ushort4*)&H[(size_t)p3.x * D + c];
    ushort4 v4 = *(const ushort4*)&H[(size_t)p4.x * D + c];
    ushort4 v5 = *(const ushort4*)&H[(size_t)p5.x * D + c];
    ushort4 v6 = *(const ushort4*)&H[(size_t)p6.x * D + c];
    ushort4 v7 = *(const ushort4*)&H[(size_t)p7.x * D + c];
    float w0 = __int_as_float(p0.y), w1 = __int_as_float(p1.y);
    float w2 = __int_as_float(p2.y), w3 = __int_as_float(p3.y);
    float w4 = __int_as_float(p4.y), w5 = __int_as_float(p5.y);
    float w6 = __int_as_float(p6.y), w7 = __int_as_float(p7.y);
    ax += w0 * bf2f(v0.x) + w1 * bf2f(v1.x) + w2 * bf2f(v2.x) + w3 * bf2f(v3.x);
    ay += w0 * bf2f(v0.y) + w1 * bf2f(v1.y) + w2 * bf2f(v2.y) + w3 * bf2f(v3.y);
    az += w0 * bf2f(v0.z) + w1 * bf2f(v1.z) + w2 * bf2f(v2.z) + w3 * bf2f(v3.z);
    aw += w0 * bf2f(v0.w) + w1 * bf2f(v1.w) + w2 * bf2f(v2.w) + w3 * bf2f(v3.w);
    ax += w4 * bf2f(v4.x) + w5 * bf2f(v5.x) + w6 * bf2f(v6.x) + w7 * bf2f(v7.x);
    ay += w4 * bf2f(v4.y) + w5 * bf2f(v5.y) + w6 * bf2f(v6.y) + w7 * bf2f(v7.y);
    az += w4 * bf2f(v4.z) + w5 * bf2f(v5.z) + w6 * bf2f(v6.z) + w7 * bf2f(v7.z);
    aw += w4 * bf2f(v4.w) + w5 * bf2f(v5.w) + w6 * bf2f(v6.w) + w7 * bf2f(v7.w);
  }
  for (; j + 4 <= len; j += 4) {
    int2 p0 = eeA[st + j];
    int2 p1 = eeA[st + j + 1];
    int2 p2 = eeA[st + j + 2];
    int2 p3 = eeA[st + j + 3];
    ushort4 v0 = *(const ushort4*)&H[(size_t)p0.x * D + c];
    ushort4 v1 = *(const ushort4*)&H[(size_t)p1.x * D + c];
    ushort4 v2 = *(const ushort4*)&H[(size_t)p2.x * D + c];
    ushort4 v3 = *(const ushort4*)&H[(size_t)p3.x * D + c];
    float w0 = __int_as_float(p0.y), w1 = __int_as_float(p1.y);
    float w2 = __int_as_float(p2.y), w3 = __int_as_float(p3.y);
    ax += w0 * bf2f(v0.x) + w1 * bf2f(v1.x) + w2 * bf2f(v2.x) + w3 * bf2f(v3.x);
    ay += w0 * bf2f(v0.y) + w1 * bf2f(v1.y) + w2 * bf2f(v2.y) + w3 * bf2f(v3.y);
    az += w0 * bf2f(v0.z) + w1 * bf2f(v1.z) + w2 * bf2f(v2.z) + w3 * bf2f(v3.z);
    aw += w0 * bf2f(v0.w) + w1 * bf2f(v1.w) + w2 * bf2f(v2.w) + w3 * bf2f(v3.w);
  }
  for (; j < len; j++) {
    int2 p = eeA[st + j];
    float w = __int_as_float(p.y);
    ushort4 v = *(const ushort4*)&H[(size_t)p.x * D + c];
    ax += w * bf2f(v.x);
    ay += w * bf2f(v.y);
    az += w * bf2f(v.z);
    aw += w * bf2f(v.w);
  }
  float dv = dinvA[base];
  float d2 = dv * dv;
  ushort4 h = *(const ushort4*)&H[(size_t)wid * D + c];
  ax += d2 * bf2f(h.x) + bias[c];
  ay += d2 * bf2f(h.y) + bias[c + 1];
  az += d2 * bf2f(h.z) + bias[c + 2];
  aw += d2 * bf2f(h.w) + bias[c + 3];
  ax = ax > 0.f ? ax : pa[c] * ax;
  ay = ay > 0.f ? ay : pa[c + 1] * ay;
  az = az > 0.f ? az : pa[c + 2] * az;
  aw = aw > 0.f ? aw : pa[c + 3] * aw;
  ushort4 o;
  o.x = f2bf(ax); o.y = f2bf(ay); o.z = f2bf(az); o.w = f2bf(aw);
  *(ushort4*)&ZhA[(size_t)t * NN * D + (size_t)wid * D + c] = o;
}

// ---------------- layer-2 fused: Agg(Zh_t) -> LDS -> @W1 + b1 -> prelu -> out ----
// grid (1563, NS). 32-row tile: xs 16896 B + ws 8192 B = 25088 B => 6 blocks/CU.
// Split-column ownership (tx*4 and 64+tx*4): each ws ds_read_b128 hits 16
// addresses at 16B stride (256B span) => 2 lanes/bank = conflict-free, vs the
// old tx*8 layout's 4-way conflict (2.56e7 conflict cycles measured in r1).
__global__ __launch_bounds__(256, 6) void l2_fused_k(
    const unsigned short* __restrict__ ZhA, const int* __restrict__ offsA,
    const int* __restrict__ cntA, const int2* __restrict__ eeA,
    const float* __restrict__ dinvA, const float* __restrict__ W,
    const float* __restrict__ bias, const float* __restrict__ pa,
    float* __restrict__ out) {
  __shared__ float xs[32 * 132];
  __shared__ float ws[16 * 128];
  const int t = blockIdx.y;
  const int r0 = blockIdx.x * 32;
  const int tid = threadIdx.x;
  const unsigned short* Z = ZhA + (size_t)t * NN * D;

  // ---- phase 1: gather 32 aggregated rows into xs ----
  {
    const int grp = tid >> 5;   // 0..7
    const int lane = tid & 31;
    const int c = lane * 4;
    for (int it = 0; it < 4; it++) {
      const int row = grp * 4 + it;
      const int node = r0 + row;
      float ax = 0.f, ay = 0.f, az = 0.f, aw = 0.f;
      if (node < NN) {
        const int base = t * NN + node;
        const int st = offsA[base];
        const int len = cntA[base];
        int j = 0;
        for (; j + 4 <= len; j += 4) {
          int2 p0 = eeA[st + j];
          int2 p1 = eeA[st + j + 1];
          int2 p2 = eeA[st + j + 2];
          int2 p3 = eeA[st + j + 3];
          ushort4 v0 = *(const ushort4*)&Z[(size_t)p0.x * D + c];
          ushort4 v1 = *(const ushort4*)&Z[(size_t)p1.x * D + c];
          ushort4 v2 = *(const ushort4*)&Z[(size_t)p2.x * D + c];
          ushort4 v3 = *(const ushort4*)&Z[(size_t)p3.x * D + c];
          float w0 = __int_as_float(p0.y), w1 = __int_as_float(p1.y);
          float w2 = __int_as_float(p2.y), w3 = __int_as_float(p3.y);
          ax += w0 * bf2f(v0.x) + w1 * bf2f(v1.x) + w2 * bf2f(v2.x) + w3 * bf2f(v3.x);
          ay += w0 * bf2f(v0.y) + w1 * bf2f(v1.y) + w2 * bf2f(v2.y) + w3 * bf2f(v3.y);
          az += w0 * bf2f(v0.z) + w1 * bf2f(v1.z) + w2 * bf2f(v2.z) + w3 * bf2f(v3.z);
          aw += w0 * bf2f(v0.w) + w1 * bf2f(v1.w) + w2 * bf2f(v2.w) + w3 * bf2f(v3.w);
        }
        for (; j < len; j++) {
          int2 p = eeA[st + j];
          float w = __int_as_float(p.y);
          ushort4 v = *(const ushort4*)&Z[(size_t)p.x * D + c];
          ax += w * bf2f(v.x);
          ay += w * bf2f(v.y);
          az += w * bf2f(v.z);
          aw += w * bf2f(v.w);
        }
        float dv = dinvA[base];
        float d2 = dv * dv;
        ushort4 h = *(const ushort4*)&Z[(size_t)node * D + c];
        ax += d2 * bf2f(h.x);
        ay += d2 * bf2f(h.y);
        az += d2 * bf2f(h.z);
        aw += d2 * bf2f(h.w);
      }
      *(float4*)&xs[row * 132 + c] = make_float4(ax, ay, az, aw);
    }
  }

  // ---- phase 2: GEMM xs @ W + bias, prelu, store fp32 ----
  const int tx = tid & 15, ty = tid >> 4;   // tx: col group, ty: 2 rows
  const int c0 = tx * 4;        // cols c0..c0+3
  const int c1 = 64 + tx * 4;   // cols c1..c1+3
  float bv[8], av[8];
#pragma unroll
  for (int j = 0; j < 4; j++) {
    bv[j] = bias[c0 + j];
    av[j] = pa[c0 + j];
    bv[4 + j] = bias[c1 + j];
    av[4 + j] = pa[c1 + j];
  }
  float acc[2][8];
#pragma unroll
  for (int i = 0; i < 2; i++)
#pragma unroll
    for (int j = 0; j < 8; j++) acc[i][j] = 0.f;

  for (int kc = 0; kc < 8; kc++) {
    __syncthreads();  // first iter: also closes phase 1
    for (int i = tid; i < 16 * 32; i += 256) {
      ((float4*)ws)[i] = ((const float4*)(W + kc * 16 * D))[i];
    }
    __syncthreads();
#pragma unroll 4
    for (int k2 = 0; k2 < 16; k2++) {
      const int k = kc * 16 + k2;
      float a[2];
#pragma unroll
      for (int j = 0; j < 2; j++) a[j] = xs[(ty * 2 + j) * 132 + k];
      float4 b0 = *(const float4*)&ws[k2 * 128 + c0];
      float4 b1 = *(const float4*)&ws[k2 * 128 + c1];
      float b[8] = {b0.x, b0.y, b0.z, b0.w, b1.x, b1.y, b1.z, b1.w};
#pragma unroll
      for (int i = 0; i < 2; i++)
#pragma unroll
        for (int j = 0; j < 8; j++) acc[i][j] += a[i] * b[j];
    }
  }
  float* outT = out + (size_t)t * NN * D;
#pragma unroll
  for (int i = 0; i < 2; i++) {
    int gr = r0 + ty * 2 + i;
    if (gr < NN) {
#pragma unroll
      for (int j = 0; j < 8; j++) {
        float v = acc[i][j] + bv[j];
        acc[i][j] = v > 0.f ? v : av[j] * v;
      }
      float4 o0 = make_float4(acc[i][0], acc[i][1], acc[i][2], acc[i][3]);
      float4 o1 = make_float4(acc[i][4], acc[i][5], acc[i][6], acc[i][7]);
      *(float4*)&outT[(size_t)gr * D + c0] = o0;
      *(float4*)&outT[(size_t)gr * D + c1] = o1;
    }
  }
}

// ---------------- launch ----------------

extern "C" void kernel_launch(void* const* d_in, const int* in_sizes, int n_in,
                              void* d_out, int out_size, void* d_ws, size_t ws_size,
                              hipStream_t stream) {
  const float* x = (const float*)d_in[0];
  const int* ei = (const int*)d_in[1];       // [4][2][NE] int32
  const float* ew = (const float*)d_in[2];   // [4][NE]
  const float* W0 = (const float*)d_in[3];
  const float* b0 = (const float*)d_in[4];
  const float* W1 = (const float*)d_in[5];
  const float* b1 = (const float*)d_in[6];
  const float* pa = (const float*)d_in[7];
  float* out = (float*)d_out;                // [4][NN][D] fp32

  // ws layout (d_ws assumed >=8B aligned; all segment sizes keep 8B alignment)
  ull* packedA = (ull*)d_ws;                              // NT ull      (1.6 MB)
  int2* eeA = (int2*)(packedA + NT);                      // NS*NE int2  (25.6 MB)
  int* posA = (int*)(eeA + (size_t)NS * NE);              // NS*NE int   (12.8 MB)
  float* dinvA = (float*)(posA + (size_t)NS * NE);        // NT f32
  int* cntA = (int*)(dinvA + NT);                         // NT
  int* offsA = cntA + NT;                                 // NT
  int* partial = offsA + NT;                              // 1024
  int* poffs = partial + 1024;                            // 1024
  unsigned short* H0h = (unsigned short*)(poffs + 1024);  // NN*D bf16 (12.8 MB)
  unsigned short* ZhA = H0h + (size_t)NN * D;             // NS*NN*D bf16 (51.2 MB)

  const int gGemm = (NN + 63) / 64;           // 782
  const int gL2 = (NN + 31) / 32;             // 1563
  const int gEdge = (NE + 255) / 256;         // 3125
  const int gInit = (NT + 255) / 256;         // 782
  const int gGather = (NN * 32 + 255) / 256;  // 6250

  // H0h = bf16(x @ W0), shared across scales (independent of CSR build)
  gemm_plain_bf16out<<<gGemm, 256, 0, stream>>>(x, W0, H0h, NN);

  // batched CSR build for all 4 scales
  initp_k<<<gInit, 256, 0, stream>>>(packedA, NT);
  countpos_all_k<<<dim3(gEdge, NS), 256, 0, stream>>>(ei, ew, packedA, posA);
  unpack_scan_k<<<SB2, 256, 0, stream>>>(packedA, dinvA, cntA, partial);
  scan_top_k<<<1, 256, 0, stream>>>(partial, poffs, SB2);
  scan_write_k<<<SB2, 256, 0, stream>>>(cntA, poffs, offsA);
  fill_all_k<<<dim3(gEdge, NS), 256, 0, stream>>>(ei, ew, dinvA, offsA, posA, eeA);

  // layer 1 (all scales): ZhA[t] = bf16(prelu(Agg_t(H0h) + b0))
  gather1_all_k<<<dim3(gGather, NS), 256, 0, stream>>>(H0h, offsA, cntA, eeA,
                                                       dinvA, b0, pa, ZhA);
  // layer 2 (all scales, fused): out[t] = prelu(Agg_t(ZhA[t]) @ W1 + b1)
  l2_fused_k<<<dim3(gL2, NS), 256, 0, stream>>>(ZhA, offsA, cntA, eeA, dinvA,
                                                W1, b1, pa, out);
}